// Round 1
// 1588.175 us; speedup vs baseline: 1.7832x; 1.7832x over previous
//
#include <hip/hip_runtime.h>
#include <hip/hip_bf16.h>

typedef __attribute__((ext_vector_type(8))) short short8;
typedef __attribute__((ext_vector_type(4))) float f32x4;

#define SEQ 40
#define IN_DIM 24
#define NKER 36
#define ENC 128
#define HID 64
#define NSTEPS 50
#define BTOT 65536

// ---- ws float-element offsets ----
#define WS_FLAG 0
#define WS_DT   1
#define WS_CW   16        // [36][3][24] f32
#define WS_CB   2608      // [36]
#define WS_E1B  2644      // [128]
#define WS_B1   2772      // [64]  ode1_b
#define WS_CZ   2836      // [64]  W1*b2
#define WS_CB2  2900      // [32]  T*reg1*b2 + reg1_b
#define WS_R2W  2932      // [32]
#define WS_R2B  2964      // [1]
#define WS_EBZ  2976      // [64]  W1*enc2_b
#define WS_PB   3040      // [32]  reg1*enc2_b
// enc1 weights in MFMA B-fragment order, k' = s*40 + o (o padded to 40), K=1600
// frag idx i = ((nt*50 + ks)*64 + lane)*8 + j ; value = W[n=nt*16+(lane&15)][k'=ks*32+(lane>>4)*8+j]
#define WS_BH   4096      // 204800 ushorts = 102400 f  (hi)
#define WS_BL   106496    // 204800 ushorts = 102400 f  (lo)
#define WS_EWZ  208896    // [64][128] f32 = W1*enc2_w
#define WS_PW   217088    // [32][128] f32 = reg1*enc2_w
#define WS_MZH  221184    // [64][64] bf16 hi (2048 f)
#define WS_MZL  223232    // [64][64] bf16 lo
#define WS_QH   225280    // [32][64] bf16 hi (1024 f)
#define WS_QL   226304    // [32][64] bf16 lo
#define WS_ZP0  262144    // [B][96] f32: z0[64] + p0[32] per row

__device__ __forceinline__ unsigned short f2bf(float f){   // RNE
  union { float f; unsigned int u; } v; v.f = f;
  unsigned int r = (v.u + 0x7FFFu + ((v.u >> 16) & 1u)) >> 16;
  return (unsigned short)r;
}
__device__ __forceinline__ float bf2f(unsigned short s){
  union { unsigned int u; float f; } v; v.u = ((unsigned int)s) << 16; return v.f;
}
__device__ __forceinline__ float tanh_fast(float x){
  float ax = fabsf(x);
  float e  = __expf(-2.0f * ax);
  float t  = (1.0f - e) * __builtin_amdgcn_rcpf(1.0f + e);
  union { float f; unsigned int u; } vx, vt;
  vx.f = x; vt.f = t; vt.u |= (vx.u & 0x80000000u);
  return vt.f;
}

// ---------------- detector ----------------
__global__ void k_detect(const void* __restrict__ x, const void* __restrict__ t_span,
                         float* __restrict__ ws){
  const unsigned int* xw = (const unsigned int*)x;
  int lane = threadIdx.x;
  int cnt = 0;
  #pragma unroll
  for (int i = 0; i < 16; i++){
    unsigned int w = xw[lane * 16 + i];
    unsigned int e = (w >> 7) & 0xFFu;
    cnt += (e >= 100u && e <= 140u) ? 1 : 0;
  }
  #pragma unroll
  for (int off = 32; off; off >>= 1) cnt += __shfl_down(cnt, off);
  if (lane == 0){
    int flag = (cnt >= 700) ? 1 : 0;
    float t0, t1;
    if (flag){
      t0 = __bfloat162float(((const __hip_bfloat16*)t_span)[0]);
      t1 = __bfloat162float(((const __hip_bfloat16*)t_span)[1]);
    } else {
      t0 = ((const float*)t_span)[0];
      t1 = ((const float*)t_span)[1];
    }
    ws[WS_FLAG] = (float)flag;
    ws[WS_DT] = (t1 - t0) / (float)NSTEPS;
  }
}

// ---------------- k0: weight convert + algebraic folds + B-frag pack ------
__global__ void k0_convert(const void* __restrict__ conv_w, const void* __restrict__ conv_b,
                           const void* __restrict__ enc1_w, const void* __restrict__ enc1_b,
                           const void* __restrict__ enc2_w, const void* __restrict__ enc2_b,
                           const void* __restrict__ ode1_w, const void* __restrict__ ode1_b,
                           const void* __restrict__ ode2_w, const void* __restrict__ ode2_b,
                           const void* __restrict__ reg1_w, const void* __restrict__ reg1_b,
                           const void* __restrict__ reg2_w, const void* __restrict__ reg2_b,
                           float* __restrict__ ws){
  const int flag = (int)ws[WS_FLAG];
  const float T = ws[WS_DT] * (float)NSTEPS;
  int t = blockIdx.x * 256 + threadIdx.x;
  int stride = gridDim.x * 256;

  #define RD(src, i) (flag ? __bfloat162float(((const __hip_bfloat16*)(src))[i]) \
                           : ((const float*)(src))[i])

  for (int i = t; i < NKER*72; i += stride){
    int o = i / 72, r = i % 72, dk = r / 24, c = r % 24;
    ws[WS_CW + i] = RD(conv_w, o*72 + c*3 + dk);
  }
  for (int i = t; i < NKER; i += stride) ws[WS_CB + i] = RD(conv_b, i);
  for (int i = t; i < ENC; i += stride) ws[WS_E1B + i] = RD(enc1_b, i);

  // enc1 B-fragments (split hi/lo bf16), k' = s*40 + o  (o in [36,40) -> 0)
  {
    unsigned short* bh = (unsigned short*)(ws + WS_BH);
    unsigned short* bl = (unsigned short*)(ws + WS_BL);
    for (int i = t; i < 8*50*64*8; i += stride){
      int j = i & 7, l = (i >> 3) & 63;
      int rem = i >> 9, ks = rem % 50, nt = rem / 50;
      int n = nt*16 + (l & 15);
      int kk = ks*32 + (l >> 4)*8 + j;
      int s = kk / 40, o = kk % 40;
      float v = (o < 36) ? RD(enc1_w, n*1440 + o*40 + s) : 0.0f;
      unsigned short h = f2bf(v);
      bh[i] = h; bl[i] = f2bf(v - bf2f(h));
    }
  }

  // EWZ = W1 * enc2_w  [64][128]
  for (int i = t; i < 64*128; i += stride){
    int n = i >> 7, j = i & 127;
    float acc = 0.f;
    for (int h = 0; h < 64; h++) acc += RD(ode1_w, n*64+h) * RD(enc2_w, h*128+j);
    ws[WS_EWZ + i] = acc;
  }
  // PW = reg1 * enc2_w  [32][128]
  for (int i = t; i < 32*128; i += stride){
    int p = i >> 7, j = i & 127;
    float acc = 0.f;
    for (int h = 0; h < 64; h++) acc += RD(reg1_w, p*64+h) * RD(enc2_w, h*128+j);
    ws[WS_PW + i] = acc;
  }
  for (int i = t; i < 64; i += stride){
    float acc = 0.f;
    for (int h = 0; h < 64; h++) acc += RD(ode1_w, i*64+h) * RD(enc2_b, h);
    ws[WS_EBZ + i] = acc;
    float acc2 = 0.f;
    for (int h = 0; h < 64; h++) acc2 += RD(ode1_w, i*64+h) * RD(ode2_b, h);
    ws[WS_CZ + i] = acc2;
    ws[WS_B1 + i] = RD(ode1_b, i);
  }
  for (int i = t; i < 32; i += stride){
    float acc = 0.f;
    for (int h = 0; h < 64; h++) acc += RD(reg1_w, i*64+h) * RD(enc2_b, h);
    ws[WS_PB + i] = acc;
    float acc2 = 0.f;
    for (int h = 0; h < 64; h++) acc2 += RD(reg1_w, i*64+h) * RD(ode2_b, h);
    ws[WS_CB2 + i] = T * acc2 + RD(reg1_b, i);
    ws[WS_R2W + i] = RD(reg2_w, i);
  }
  if (t == 0) ws[WS_R2B] = RD(reg2_b, 0);

  // Mz = W1*W2 [64][64], split hi/lo bf16
  unsigned short* mzh = (unsigned short*)(ws + WS_MZH);
  unsigned short* mzl = (unsigned short*)(ws + WS_MZL);
  for (int i = t; i < 64*64; i += stride){
    int a = i >> 6, b = i & 63;
    float acc = 0.f;
    for (int h = 0; h < 64; h++) acc += RD(ode1_w, a*64+h) * RD(ode2_w, h*64+b);
    unsigned short hi = f2bf(acc);
    mzh[i] = hi; mzl[i] = f2bf(acc - bf2f(hi));
  }
  // Q = reg1*W2 [32][64], split hi/lo bf16
  unsigned short* qh = (unsigned short*)(ws + WS_QH);
  unsigned short* ql = (unsigned short*)(ws + WS_QL);
  for (int i = t; i < 32*64; i += stride){
    int p = i >> 6, b = i & 63;
    float acc = 0.f;
    for (int h = 0; h < 64; h++) acc += RD(reg1_w, p*64+h) * RD(ode2_w, h*64+b);
    unsigned short hi = f2bf(acc);
    qh[i] = hi; ql[i] = f2bf(acc - bf2f(hi));
  }
  #undef RD
}

// ---------------- k1: conv+silu -> split-bf16 MFMA enc1 -> folded enc2 ----
// 1024 blocks x 256 thr (4 waves), 64 rows/block.
// Chunk = 4 s-columns -> klocal in [0,160) (o padded to 40), 5 MFMA k-steps.
// Wave gu: conv s-column = c*4+gu, 64 rows (lane = row).
// MFMA: wave (wm=gu>>1, wn=gu&1): rows wm*32 + mt*16, cols wn*64 + nt*16.
// A-frag: m = lane&15, k = (lane>>4)*8 + j ; LDS XOR-swizzled at 8-k-block granularity.
__launch_bounds__(256, 4)
__global__ void k1_encoder(const void* __restrict__ x,
                           const float* __restrict__ ws,
                           float* __restrict__ zp0){
  __shared__ float lds[10240];                       // 40 KB: Ahi/Alo, later e1[64][129]
  unsigned short* Ahi = (unsigned short*)lds;        // [64][160] ushort
  unsigned short* Alo = Ahi + 64*160;
  const int flag = (int)ws[WS_FLAG];
  const int t = threadIdx.x;
  const int lane = t & 63;
  const int gu = __builtin_amdgcn_readfirstlane(t >> 6);   // wave id, SGPR
  const int wm = gu >> 1, wn = gu & 1;
  const int l15 = lane & 15, q = lane >> 4;
  const int r = lane;                                // conv/epilogue row 0..63
  const long rowbase = (long)blockIdx.x * 64;

  f32x4 acc[2][4];
  #pragma unroll
  for (int mt = 0; mt < 2; mt++)
    #pragma unroll
    for (int nt = 0; nt < 4; nt++)
      acc[mt][nt] = (f32x4){0.f, 0.f, 0.f, 0.f};

  const unsigned short* BH = (const unsigned short*)(ws + WS_BH);
  const unsigned short* BL = (const unsigned short*)(ws + WS_BL);
  const float* CW = ws + WS_CW;
  const float* CB = ws + WS_CB;

  float xc[24];
  auto loadcol = [&](int col){
    if (col >= 0 && col < SEQ){
      if (flag){
        const __hip_bfloat16* xp = (const __hip_bfloat16*)x + (rowbase + r)*(SEQ*IN_DIM) + col*IN_DIM;
        const uint4* px = (const uint4*)xp;
        #pragma unroll
        for (int w8 = 0; w8 < 3; w8++){
          uint4 u = px[w8];
          unsigned int uu[4] = {u.x, u.y, u.z, u.w};
          #pragma unroll
          for (int e = 0; e < 4; e++){
            union { unsigned int i; float f; } lo, hi;
            lo.i = uu[e] << 16; hi.i = uu[e] & 0xffff0000u;
            xc[w8*8 + 2*e] = lo.f; xc[w8*8 + 2*e + 1] = hi.f;
          }
        }
      } else {
        const float* xp = (const float*)x + (rowbase + r)*(SEQ*IN_DIM) + col*IN_DIM;
        #pragma unroll
        for (int w4 = 0; w4 < 6; w4++){
          float4 v = ((const float4*)xp)[w4];
          xc[4*w4] = v.x; xc[4*w4+1] = v.y; xc[4*w4+2] = v.z; xc[4*w4+3] = v.w;
        }
      }
    } else {
      #pragma unroll
      for (int cc = 0; cc < 24; cc++) xc[cc] = 0.f;
    }
  };

  // XOR swizzle on 8-k blocks; row stride = 20 blocks (not mult of 8):
  // blocks 0-15 xor (r&7), blocks 16-19 xor (r&3) -- writer and reader agree.
  auto swzb = [](int blk, int rw){ return blk ^ ((blk < 16) ? (rw & 7) : (rw & 3)); };

  #pragma unroll 1
  for (int c = 0; c < 10; c++){
    __syncthreads();   // prev chunk's MFMA reads done
    // ---- conv phase: row r, s-column = c*4 + gu ----
    {
      const int s = c*4 + gu;
      float accv[36];
      #pragma unroll
      for (int o = 0; o < 36; o++) accv[o] = CB[o];
      #pragma unroll 1
      for (int dk = 0; dk < 3; dk++){
        loadcol(s - 1 + dk);
        const float* wdk = CW + dk*24;
        #pragma unroll
        for (int o = 0; o < 36; o++){
          const float* wo = wdk + o*72;
          float a = accv[o];
          #pragma unroll
          for (int ci = 0; ci < 24; ci++) a += wo[ci] * xc[ci];
          accv[o] = a;
        }
      }
      const int kb0 = gu * 40;
      #pragma unroll
      for (int o = 0; o < 40; o += 2){
        unsigned int hpack, lpack;
        if (o < 36){
          float v0 = accv[o];     v0 = v0 * __builtin_amdgcn_rcpf(1.0f + __expf(-v0));
          float v1 = accv[o + 1]; v1 = v1 * __builtin_amdgcn_rcpf(1.0f + __expf(-v1));
          unsigned short h0 = f2bf(v0), h1 = f2bf(v1);
          unsigned short l0 = f2bf(v0 - bf2f(h0)), l1 = f2bf(v1 - bf2f(h1));
          hpack = (unsigned int)h0 | ((unsigned int)h1 << 16);
          lpack = (unsigned int)l0 | ((unsigned int)l1 << 16);
        } else { hpack = 0u; lpack = 0u; }
        int k = kb0 + o;
        int idx = r*160 + (swzb(k >> 3, r) << 3) + (k & 7);
        *(unsigned int*)(Ahi + idx) = hpack;
        *(unsigned int*)(Alo + idx) = lpack;
      }
    }
    __syncthreads();
    // ---- MFMA phase: 5 k-steps of 32 ----
    #pragma unroll
    for (int ksl = 0; ksl < 5; ksl++){
      const int ks = c*5 + ksl;
      short8 ah[2], al[2];
      #pragma unroll
      for (int mt = 0; mt < 2; mt++){
        int rr = wm*32 + mt*16 + l15;
        int kb = ksl*4 + q;
        int idx = rr*160 + (swzb(kb, rr) << 3);
        ah[mt] = *(const short8*)(Ahi + idx);
        al[mt] = *(const short8*)(Alo + idx);
      }
      #pragma unroll
      for (int nt = 0; nt < 4; nt++){
        int fo = (((wn*4 + nt)*50 + ks)*64 + lane) << 3;
        short8 bh = *(const short8*)(BH + fo);
        short8 bl = *(const short8*)(BL + fo);
        #pragma unroll
        for (int mt = 0; mt < 2; mt++){
          acc[mt][nt] = __builtin_amdgcn_mfma_f32_16x16x32_bf16(ah[mt], bh, acc[mt][nt], 0, 0, 0);
          acc[mt][nt] = __builtin_amdgcn_mfma_f32_16x16x32_bf16(al[mt], bh, acc[mt][nt], 0, 0, 0);
          acc[mt][nt] = __builtin_amdgcn_mfma_f32_16x16x32_bf16(ah[mt], bl, acc[mt][nt], 0, 0, 0);
        }
      }
    }
  }

  // ---- e1 = relu(acc + e1_b) -> LDS [64][129] ----
  __syncthreads();
  float* e1buf = lds;
  #pragma unroll
  for (int mt = 0; mt < 2; mt++){
    #pragma unroll
    for (int nt = 0; nt < 4; nt++){
      int col = wn*64 + nt*16 + l15;
      float bias = ws[WS_E1B + col];
      #pragma unroll
      for (int r2 = 0; r2 < 4; r2++){
        int row = wm*32 + mt*16 + q*4 + r2;
        float v = acc[mt][nt][r2] + bias;
        e1buf[row*129 + col] = v > 0.0f ? v : 0.0f;
      }
    }
  }
  __syncthreads();

  // ---- folded enc2: zp[n] = [EWZ;PW] . e1 + [EBZ;PB], n in [gu*24, gu*24+24) ----
  {
    const int n0 = gu * 24;
    float accs[24];
    #pragma unroll
    for (int i = 0; i < 24; i++){
      int n = n0 + i;
      accs[i] = (n < 64) ? ws[WS_EBZ + n] : ws[WS_PB + (n - 64)];
    }
    const float* e1r = e1buf + r*129;
    #pragma unroll 4
    for (int j = 0; j < 128; j++){
      float e = e1r[j];
      #pragma unroll
      for (int i = 0; i < 24; i++){
        int n = n0 + i;
        const float* wp = (n < 64) ? (ws + WS_EWZ + n*128) : (ws + WS_PW + (n - 64)*128);
        accs[i] += e * wp[j];
      }
    }
    float* dst = zp0 + (rowbase + r)*96 + n0;
    #pragma unroll
    for (int i = 0; i < 24; i += 4){
      f32x4 v = {accs[i], accs[i+1], accs[i+2], accs[i+3]};
      *(f32x4*)(dst + i) = v;
    }
  }
}

// ---------------- k2: 50 dopri5 steps on z (split-bf16 MFMA) + regressor --
// one wave/block, 16 rows/wave. z' = Mz*tanh(z+b1) + cz ; s += dt*bw_i*u_i
// C/D: elem (m,n): n = nt*16+(lane&15), m = (lane>>4)*4 + r
// A:   A[m][k]: m = lane&15, k = kc*32 + (lane>>4)*8 + j
// LDS tile [k][m'] stride 17, m' = m ^ (8*((k>>2)&1))
__launch_bounds__(64, 2)
__global__ void k2_ode(const float* __restrict__ ws,
                       const float* __restrict__ zp0,
                       float* __restrict__ out){
  __shared__ float scr[64*17];
  const int tid = threadIdx.x;
  const int l = tid & 15, q = tid >> 4;
  const int sl8 = 8 * ((l >> 2) & 1);
  const int rowbase = blockIdx.x * 16;

  short8 mh[2][4], ml[2][4];
  {
    const short8* pmh = (const short8*)(ws + WS_MZH);
    const short8* pml = (const short8*)(ws + WS_MZL);
    #pragma unroll
    for (int nt = 0; nt < 4; nt++){
      int n = nt*16 + l;
      #pragma unroll
      for (int kc = 0; kc < 2; kc++){
        int idx = n*8 + kc*4 + q;
        mh[kc][nt] = pmh[idx];
        ml[kc][nt] = pml[idx];
      }
    }
  }
  float b1v[4], czv[4];
  #pragma unroll
  for (int nt = 0; nt < 4; nt++){
    b1v[nt] = ws[WS_B1 + nt*16 + l];
    czv[nt] = ws[WS_CZ + nt*16 + l];
  }
  const float dt = ws[WS_DT];

  float z[16], s[16];
  #pragma unroll
  for (int i = 0; i < 16; i++){
    int nt = i >> 2, r = i & 3;
    z[i] = zp0[(long)(rowbase + q*4 + r) * 96 + nt*16 + l];
    s[i] = 0.0f;
  }

  auto put_tile = [&](const float* u){
    __syncthreads();
    #pragma unroll
    for (int nt = 0; nt < 4; nt++){
      int base = (nt*16 + l)*17 + ((q*4) ^ sl8);
      scr[base+0] = u[nt*4+0];
      scr[base+1] = u[nt*4+1];
      scr[base+2] = u[nt*4+2];
      scr[base+3] = u[nt*4+3];
    }
    __syncthreads();
  };
  auto get_frags = [&](short8& a0h, short8& a1h, short8& a0l, short8& a1l){
    union { short sv[8]; short8 v; } u0h, u1h, u0l, u1l;
    #pragma unroll
    for (int j = 0; j < 8; j++){
      int mp = (j < 4) ? l : (l ^ 8);
      float v0 = scr[(q*8 + j)*17 + mp];
      float v1 = scr[(q*8 + j + 32)*17 + mp];
      unsigned short h0 = f2bf(v0);
      unsigned short h1 = f2bf(v1);
      u0h.sv[j] = (short)h0; u0l.sv[j] = (short)f2bf(v0 - bf2f(h0));
      u1h.sv[j] = (short)h1; u1l.sv[j] = (short)f2bf(v1 - bf2f(h1));
    }
    a0h = u0h.v; a1h = u1h.v; a0l = u0l.v; a1l = u1l.v;
  };

  auto feval = [&](const float* v, float* g, float w){
    float u[16];
    #pragma unroll
    for (int nt = 0; nt < 4; nt++){
      #pragma unroll
      for (int r = 0; r < 4; r++) u[nt*4+r] = tanh_fast(v[nt*4+r] + b1v[nt]);
    }
    if (w != 0.0f){
      #pragma unroll
      for (int i = 0; i < 16; i++) s[i] += w * u[i];
    }
    put_tile(u);
    short8 a0h, a1h, a0l, a1l;
    get_frags(a0h, a1h, a0l, a1l);
    #pragma unroll
    for (int nt = 0; nt < 4; nt++){
      f32x4 c = {0.f, 0.f, 0.f, 0.f};
      c = __builtin_amdgcn_mfma_f32_16x16x32_bf16(a0h, mh[0][nt], c, 0, 0, 0);
      c = __builtin_amdgcn_mfma_f32_16x16x32_bf16(a1h, mh[1][nt], c, 0, 0, 0);
      c = __builtin_amdgcn_mfma_f32_16x16x32_bf16(a0l, mh[0][nt], c, 0, 0, 0);
      c = __builtin_amdgcn_mfma_f32_16x16x32_bf16(a1l, mh[1][nt], c, 0, 0, 0);
      c = __builtin_amdgcn_mfma_f32_16x16x32_bf16(a0h, ml[0][nt], c, 0, 0, 0);
      c = __builtin_amdgcn_mfma_f32_16x16x32_bf16(a1h, ml[1][nt], c, 0, 0, 0);
      #pragma unroll
      for (int r = 0; r < 4; r++) g[nt*4+r] = c[r] + czv[nt];
    }
  };

  const float c21 = dt * 0.2f;
  const float c31 = dt * (3.0f/40.0f),      c32 = dt * (9.0f/40.0f);
  const float c41 = dt * (44.0f/45.0f),     c42 = dt * (-56.0f/15.0f),   c43 = dt * (32.0f/9.0f);
  const float c51 = dt * (19372.0f/6561.0f), c52 = dt * (-25360.0f/2187.0f),
              c53 = dt * (64448.0f/6561.0f), c54 = dt * (-212.0f/729.0f);
  const float c61 = dt * (9017.0f/3168.0f),  c62 = dt * (-355.0f/33.0f),
              c63 = dt * (46732.0f/5247.0f), c64 = dt * (49.0f/176.0f),
              c65 = dt * (-5103.0f/18656.0f);
  const float d1 = dt * (35.0f/384.0f), d3 = dt * (500.0f/1113.0f), d4 = dt * (125.0f/192.0f),
              d5 = dt * (-2187.0f/6784.0f), d6 = dt * (11.0f/84.0f);

  float g1[16], g2[16], g3[16], g4[16], g5[16], g6[16], yt[16];

  #pragma unroll 1
  for (int st = 0; st < NSTEPS; st++){
    feval(z, g1, d1);
    #pragma unroll
    for (int i = 0; i < 16; i++) yt[i] = z[i] + c21*g1[i];
    feval(yt, g2, 0.0f);
    #pragma unroll
    for (int i = 0; i < 16; i++) yt[i] = z[i] + c31*g1[i] + c32*g2[i];
    feval(yt, g3, d3);
    #pragma unroll
    for (int i = 0; i < 16; i++) yt[i] = z[i] + c41*g1[i] + c42*g2[i] + c43*g3[i];
    feval(yt, g4, d4);
    #pragma unroll
    for (int i = 0; i < 16; i++) yt[i] = z[i] + c51*g1[i] + c52*g2[i] + c53*g3[i] + c54*g4[i];
    feval(yt, g5, d5);
    #pragma unroll
    for (int i = 0; i < 16; i++) yt[i] = z[i] + c61*g1[i] + c62*g2[i] + c63*g3[i] + c64*g4[i] + c65*g5[i];
    feval(yt, g6, d6);
    #pragma unroll
    for (int i = 0; i < 16; i++) z[i] = z[i] + d1*g1[i] + d3*g3[i] + d4*g4[i] + d5*g5[i] + d6*g6[i];
  }

  // ---- regressor: r = relu(p0 + Q*s + cb); out = reg2*r + r2b ----
  {
    put_tile(s);
    short8 a0h, a1h, a0l, a1l;
    get_frags(a0h, a1h, a0l, a1l);
    const short8* pqh = (const short8*)(ws + WS_QH);
    const short8* pql = (const short8*)(ws + WS_QL);
    float rr[2][4];
    #pragma unroll
    for (int nt2 = 0; nt2 < 2; nt2++){
      int n = nt2*16 + l;
      short8 qh0 = pqh[n*8 + q];
      short8 qh1 = pqh[n*8 + 4 + q];
      short8 ql0 = pql[n*8 + q];
      short8 ql1 = pql[n*8 + 4 + q];
      f32x4 c = {0.f, 0.f, 0.f, 0.f};
      c = __builtin_amdgcn_mfma_f32_16x16x32_bf16(a0h, qh0, c, 0, 0, 0);
      c = __builtin_amdgcn_mfma_f32_16x16x32_bf16(a1h, qh1, c, 0, 0, 0);
      c = __builtin_amdgcn_mfma_f32_16x16x32_bf16(a0l, qh0, c, 0, 0, 0);
      c = __builtin_amdgcn_mfma_f32_16x16x32_bf16(a1l, qh1, c, 0, 0, 0);
      c = __builtin_amdgcn_mfma_f32_16x16x32_bf16(a0h, ql0, c, 0, 0, 0);
      c = __builtin_amdgcn_mfma_f32_16x16x32_bf16(a1h, ql1, c, 0, 0, 0);
      float cbn = ws[WS_CB2 + n];
      #pragma unroll
      for (int r = 0; r < 4; r++){
        float p0 = zp0[(long)(rowbase + q*4 + r) * 96 + 64 + n];
        float v = c[r] + cbn + p0;
        rr[nt2][r] = v > 0.0f ? v : 0.0f;
      }
    }
    float w2v0 = ws[WS_R2W + l];
    float w2v1 = ws[WS_R2W + 16 + l];
    float part[4];
    #pragma unroll
    for (int r = 0; r < 4; r++) part[r] = rr[0][r]*w2v0 + rr[1][r]*w2v1;
    #pragma unroll
    for (int off = 1; off < 16; off <<= 1){
      #pragma unroll
      for (int r = 0; r < 4; r++) part[r] += __shfl_xor(part[r], off);
    }
    float r2b = ws[WS_R2B];
    if (l == 0){
      #pragma unroll
      for (int r = 0; r < 4; r++)
        out[rowbase + q*4 + r] = part[r] + r2b;
    }
  }
}

// ---------------------------------------------------------------------------
extern "C" void kernel_launch(void* const* d_in, const int* in_sizes, int n_in,
                              void* d_out, int out_size, void* d_ws, size_t ws_size,
                              hipStream_t stream){
  (void)in_sizes; (void)n_in; (void)out_size; (void)ws_size;
  float* ws = (float*)d_ws;

  k_detect<<<dim3(1), dim3(64), 0, stream>>>(d_in[0], d_in[1], ws);
  k0_convert<<<dim3(64), dim3(256), 0, stream>>>(
      d_in[2], d_in[3], d_in[4], d_in[5], d_in[6], d_in[7],
      d_in[8], d_in[9], d_in[10], d_in[11], d_in[12], d_in[13],
      d_in[14], d_in[15], ws);
  k1_encoder<<<dim3(BTOT/64), dim3(256), 0, stream>>>(d_in[0], ws, ws + WS_ZP0);
  k2_ode<<<dim3(BTOT/16), dim3(64), 0, stream>>>(ws, ws + WS_ZP0, (float*)d_out);
}